// Round 3
// baseline (719.402 us; speedup 1.0000x reference)
//
#include <hip/hip_runtime.h>

// Problem constants: N=128, T=2048, D=88
#define NN 128
#define TT 2048
#define DD 88
#define ROWS_PER_BLK 128
#define F4_PER_ROW 22                             // 88 floats = 22 float4
#define F4_PER_TILE (ROWS_PER_BLK * F4_PER_ROW)   // 2816 = 11 * 256
#define BLKS_PER_N (TT / ROWS_PER_BLK)            // 16
#define GRID (NN * BLKS_PER_N)                    // 2048

typedef float f4 __attribute__((ext_vector_type(4)));

// ws layout (float/uint words):
//   [0..127]    tp_total[n]   (f32, zeroed)
//   [128..255]  ticket[n]     (u32, zeroed)
//   [256]       ticket2       (u32, zeroed)
//   [260..387]  acc[n]        (f32)
//   [512.. ]    fpfn[N*T]     (f32)
#define TP_OFF 0
#define TICKET_OFF 128
#define TICKET2_OFF 256
#define ACC_OFF 260
#define FPFN_OFF 512

__global__ __launch_bounds__(256) void acc_fused_kernel(
    const float* __restrict__ out, const float* __restrict__ tgt,
    const int* __restrict__ mask, float* __restrict__ ws,
    float* __restrict__ outp) {
  __shared__ float lds_x[F4_PER_TILE];
  __shared__ float s_tp[4];
  __shared__ unsigned int s_old, s_old2;

  float* tp_total = ws + TP_OFF;
  unsigned int* ticket = (unsigned int*)(ws + TICKET_OFF);
  unsigned int* ticket2 = (unsigned int*)(ws + TICKET2_OFF);
  float* acc = ws + ACC_OFF;
  float* fpfn = ws + FPFN_OFF;

  const int tid = threadIdx.x;
  const int blk = blockIdx.x;
  const int n = blk / BLKS_PER_N;
  const size_t tile_f4 = (size_t)blk * F4_PER_TILE;
  const f4* __restrict__ o4 = (const f4*)out;
  const f4* __restrict__ g4 = (const f4*)tgt;

  // ---- Phase 1: coalesced float4 stream; per-float4 mismatch count -> LDS ----
  float tp = 0.f;
#pragma unroll
  for (int it = 0; it < 11; ++it) {
    const int f = it * 256 + tid;
    const f4 o = o4[tile_f4 + f];
    const f4 g = g4[tile_f4 + f];
    float x = 0.f;
    {
      const float pf = (o.x > 0.f) ? 1.f : 0.f;
      x += fabsf(pf - g.x);
      tp = fmaf(pf, g.x, tp);
    }
    {
      const float pf = (o.y > 0.f) ? 1.f : 0.f;
      x += fabsf(pf - g.y);
      tp = fmaf(pf, g.y, tp);
    }
    {
      const float pf = (o.z > 0.f) ? 1.f : 0.f;
      x += fabsf(pf - g.z);
      tp = fmaf(pf, g.z, tp);
    }
    {
      const float pf = (o.w > 0.f) ? 1.f : 0.f;
      x += fabsf(pf - g.w);
      tp = fmaf(pf, g.w, tp);
    }
    lds_x[f] = x;
  }
  __syncthreads();

  // ---- Phase 2: per-row fpfn (thread pair per row) ----
  {
    const int r = tid >> 1;
    const int s = tid & 1;
    float v = 0.f;
#pragma unroll
    for (int i = 0; i < 11; ++i) v += lds_x[r * F4_PER_ROW + s * 11 + i];
    v += __shfl_down(v, 1, 64);
    if (s == 0) fpfn[(size_t)blk * ROWS_PER_BLK + r] = v;
  }

  // ---- tp block-reduce -> atomicAdd (exact integer counts, order-free) ----
  for (int off = 32; off > 0; off >>= 1) tp += __shfl_down(tp, off, 64);
  const int lane = tid & 63, wave = tid >> 6;
  if (lane == 0) s_tp[wave] = tp;
  __syncthreads();
  if (tid == 0) atomicAdd(&tp_total[n], s_tp[0] + s_tp[1] + s_tp[2] + s_tp[3]);

  // ---- release + ticket: 16th block of this n finalizes ----
  __threadfence();
  if (tid == 0) s_old = atomicAdd(&ticket[n], 1u);
  __syncthreads();
  if (s_old != (unsigned)(BLKS_PER_N - 1)) return;

  // ---- Finalize n ----
  __threadfence();  // acquire: see all 16 producers' fpfn/tp writes
  float* sred = lds_x;

  // T_i from mask row (512 int4, 2 per thread)
  const int4* m4 = (const int4*)(mask + (size_t)n * TT);
  int ti = 0;
#pragma unroll
  for (int it = 0; it < 2; ++it) {
    const int4 v = m4[it * 256 + tid];
    ti += v.x + v.y + v.z + v.w;
  }
  sred[tid] = (float)ti;
  __syncthreads();
  for (int s = 128; s > 0; s >>= 1) {
    if (tid < s) sred[tid] += sred[tid + s];
    __syncthreads();
  }
  const float fTi = sred[0];
  const int Ti = (int)fTi;
  const float tpn = tp_total[n];
  __syncthreads();

  // ratio sum over valid timesteps
  const float* __restrict__ fr = fpfn + (size_t)n * TT;
  float a = 0.f;
  for (int t = tid; t < Ti; t += 256) a += tpn / (tpn + fr[t]);
  sred[tid] = a;
  __syncthreads();
  for (int s = 128; s > 0; s >>= 1) {
    if (tid < s) sred[tid] += sred[tid + s];
    __syncthreads();
  }
  if (tid == 0) {
    acc[n] = sred[0] / fTi;
    __threadfence();  // release acc[n]
    s_old2 = atomicAdd(ticket2, 1u);
  }
  __syncthreads();
  if (s_old2 != (unsigned)(NN - 1)) return;

  // ---- Super-finalize: last finalizer sums acc[0..127], single plain store ----
  __threadfence();  // acquire acc[]
  sred[tid] = (tid < NN) ? acc[tid] : 0.f;
  __syncthreads();
  for (int s = 128; s > 0; s >>= 1) {
    if (tid < s) sred[tid] += sred[tid + s];
    __syncthreads();
  }
  if (tid == 0) outp[0] = sred[0];
}

extern "C" void kernel_launch(void* const* d_in, const int* in_sizes, int n_in,
                              void* d_out, int out_size, void* d_ws, size_t ws_size,
                              hipStream_t stream) {
  const float* output = (const float*)d_in[0];
  const float* target = (const float*)d_in[1];
  const int* mask = (const int*)d_in[2];
  float* out = (float*)d_out;
  float* ws = (float*)d_ws;

  // zero tp_total / ticket / ticket2 / acc (first 512 words); fpfn needs no init
  hipMemsetAsync(d_ws, 0, 512 * sizeof(float), stream);
  acc_fused_kernel<<<GRID, 256, 0, stream>>>(output, target, mask, ws, out);
}

// Round 4
// 204.162 us; speedup vs baseline: 3.5237x; 3.5237x over previous
//
#include <hip/hip_runtime.h>

// Problem constants: N=128, T=2048, D=88
#define NN 128
#define TT 2048
#define DD 88
#define ROWS_PER_BLK 128
#define F4_PER_ROW 22                             // 88 floats = 22 float4
#define F4_PER_TILE (ROWS_PER_BLK * F4_PER_ROW)   // 2816 = 11 * 256
#define BLKS_PER_N (TT / ROWS_PER_BLK)            // 16
#define K1_BLOCKS (NN * BLKS_PER_N)               // 2048

typedef float f4 __attribute__((ext_vector_type(4)));

// ws layout (floats): tp_part[K1_BLOCKS] | acc[NN] | fpfn[N*T]
// Everything is written before being read within one call — no init needed.

// K1: coalesced float4 streaming, ALL 22 loads issued before any consumption
// (register arrays + launch_bounds(256,4) -> VGPR cap 128) to maximize
// memory-level parallelism. Per-float4 mismatch -> LDS; per-row fpfn out.
__global__ __launch_bounds__(256, 4) void acc_rowstats_kernel(
    const float* __restrict__ out, const float* __restrict__ tgt,
    float* __restrict__ fpfn, float* __restrict__ tp_part) {
  __shared__ float lds_x[F4_PER_TILE];
  const int tid = threadIdx.x;
  const int blk = blockIdx.x;
  const size_t base = (size_t)blk * F4_PER_TILE + tid;
  const f4* __restrict__ o4 = (const f4*)out;
  const f4* __restrict__ g4 = (const f4*)tgt;

  // ---- issue all 22 independent loads ----
  f4 o[11], g[11];
#pragma unroll
  for (int it = 0; it < 11; ++it) {
    o[it] = o4[base + it * 256];
    g[it] = g4[base + it * 256];
  }

  // ---- consume ----
  float tp = 0.f;
#pragma unroll
  for (int it = 0; it < 11; ++it) {
    float x = 0.f;
    {
      const float pf = (o[it].x > 0.f) ? 1.f : 0.f;
      x += fabsf(pf - g[it].x);
      tp = fmaf(pf, g[it].x, tp);
    }
    {
      const float pf = (o[it].y > 0.f) ? 1.f : 0.f;
      x += fabsf(pf - g[it].y);
      tp = fmaf(pf, g[it].y, tp);
    }
    {
      const float pf = (o[it].z > 0.f) ? 1.f : 0.f;
      x += fabsf(pf - g[it].z);
      tp = fmaf(pf, g[it].z, tp);
    }
    {
      const float pf = (o[it].w > 0.f) ? 1.f : 0.f;
      x += fabsf(pf - g[it].w);
      tp = fmaf(pf, g[it].w, tp);
    }
    lds_x[it * 256 + tid] = x;
  }
  __syncthreads();

  // ---- per-row fpfn: thread pair (2r, 2r+1) per row ----
  {
    const int r = tid >> 1;
    const int s = tid & 1;
    float v = 0.f;
#pragma unroll
    for (int i = 0; i < 11; ++i) v += lds_x[r * F4_PER_ROW + s * 11 + i];
    v += __shfl_down(v, 1, 64);
    if (s == 0) fpfn[(size_t)blk * ROWS_PER_BLK + r] = v;
  }

  // ---- tp block-reduce -> deterministic per-block partial ----
  for (int off = 32; off > 0; off >>= 1) tp += __shfl_down(tp, off, 64);
  __shared__ float s_tp[4];
  const int lane = tid & 63, wave = tid >> 6;
  if (lane == 0) s_tp[wave] = tp;
  __syncthreads();
  if (tid == 0) tp_part[blk] = s_tp[0] + s_tp[1] + s_tp[2] + s_tp[3];
}

// K2: one block per n -> acc[n]. No atomics.
__global__ __launch_bounds__(256) void acc_finalize_kernel(
    const int* __restrict__ mask, const float* __restrict__ fpfn,
    const float* __restrict__ tp_part, float* __restrict__ acc) {
  const int n = blockIdx.x;
  const int tid = threadIdx.x;
  __shared__ float sa[256], sb[256];

  // T_i via int4 loads (2048 ints = 512 int4)
  const int4* m4 = (const int4*)(mask + (size_t)n * TT);
  int ti = 0;
#pragma unroll
  for (int it = 0; it < 2; ++it) {
    const int4 v = m4[it * 256 + tid];
    ti += v.x + v.y + v.z + v.w;
  }
  const float tpv = (tid < BLKS_PER_N) ? tp_part[n * BLKS_PER_N + tid] : 0.f;

  sa[tid] = (float)ti;
  sb[tid] = tpv;
  __syncthreads();
  for (int s = 128; s > 0; s >>= 1) {
    if (tid < s) { sa[tid] += sa[tid + s]; sb[tid] += sb[tid + s]; }
    __syncthreads();
  }
  const float fTi = sa[0];
  const float tp = sb[0];
  const int Ti = (int)fTi;
  __syncthreads();

  const float* __restrict__ fr = fpfn + (size_t)n * TT;
  float a = 0.f;
  for (int t = tid; t < Ti; t += 256) a += tp / (tp + fr[t]);
  sa[tid] = a;
  __syncthreads();
  for (int s = 128; s > 0; s >>= 1) {
    if (tid < s) sa[tid] += sa[tid + s];
    __syncthreads();
  }
  if (tid == 0) acc[n] = sa[0] / fTi;
}

// K3: single block sums acc[0..127] -> out[0] (plain store, no contention)
__global__ __launch_bounds__(128) void acc_sum_kernel(
    const float* __restrict__ acc, float* __restrict__ out) {
  const int tid = threadIdx.x;
  __shared__ float sred[128];
  sred[tid] = acc[tid];
  __syncthreads();
  for (int s = 64; s > 0; s >>= 1) {
    if (tid < s) sred[tid] += sred[tid + s];
    __syncthreads();
  }
  if (tid == 0) out[0] = sred[0];
}

extern "C" void kernel_launch(void* const* d_in, const int* in_sizes, int n_in,
                              void* d_out, int out_size, void* d_ws, size_t ws_size,
                              hipStream_t stream) {
  const float* output = (const float*)d_in[0];
  const float* target = (const float*)d_in[1];
  const int* mask = (const int*)d_in[2];
  float* out = (float*)d_out;

  float* tp_part = (float*)d_ws;
  float* acc = tp_part + K1_BLOCKS;
  float* fpfn = acc + NN;

  acc_rowstats_kernel<<<K1_BLOCKS, 256, 0, stream>>>(output, target, fpfn, tp_part);
  acc_finalize_kernel<<<NN, 256, 0, stream>>>(mask, fpfn, tp_part, acc);
  acc_sum_kernel<<<1, 128, 0, stream>>>(acc, out);
}

// Round 5
// 202.965 us; speedup vs baseline: 3.5445x; 1.0059x over previous
//
#include <hip/hip_runtime.h>
#include <stdint.h>

// Problem constants: N=128, T=2048, D=88
#define NN 128
#define TT 2048
#define DD 88
#define ROWS 32                      // timesteps per K1 block
#define F4_ROW 22                    // float4 per row (88 floats)
#define F4_TILE (ROWS * F4_ROW)      // 704 f4 = 11264 B per array
#define INSTR_PER_ARR 11             // 11 x 1KB global_load_lds per array
#define K1_BLOCKS (NN * TT / ROWS)   // 8192
#define PARTS_PER_N (TT / ROWS)      // 64 tp partials per n

typedef float f4 __attribute__((ext_vector_type(4)));
typedef const __attribute__((address_space(1))) uint32_t guint;
typedef __attribute__((address_space(3))) uint32_t luint;

// K1: async global->LDS staging (no VGPR round-trip => all 1KB loads of a
// wave stay in flight), then per-row fpfn + per-block tp partial.
__global__ __launch_bounds__(256) void acc_rowstats_kernel(
    const float* __restrict__ outp, const float* __restrict__ tgt,
    float* __restrict__ fpfn, float* __restrict__ tp_part) {
  __shared__ f4 lds_o[F4_TILE];
  __shared__ f4 lds_g[F4_TILE];
  __shared__ float s_tp[4];

  const int tid = threadIdx.x;
  const int lane = tid & 63;
  const int wave = tid >> 6;
  const int blk = blockIdx.x;
  const size_t tile_f = (size_t)blk * (ROWS * DD);  // element offset of tile

  // ---- stage 22 x 1KB direct-to-LDS (waves 0,1: 6 instrs; waves 2,3: 5) ----
  for (int j = wave; j < 2 * INSTR_PER_ARR; j += 4) {
    const int is_g = (j >= INSTR_PER_ARR) ? 1 : 0;
    const int idx = j - is_g * INSTR_PER_ARR;        // wave-uniform
    const float* src = (is_g ? tgt : outp) + tile_f + idx * 256;
    float* dst = (is_g ? (float*)lds_g : (float*)lds_o) + idx * 256;
    // lane l: global src + l*16B  ->  LDS uniform base + l*16B
    __builtin_amdgcn_global_load_lds((guint*)src + lane * 4, (luint*)dst,
                                     16, 0, 0);
  }
  __syncthreads();  // compiler drains vmcnt before the barrier

  // ---- consume from LDS: 8 threads per row ----
  const int r = tid >> 3;  // 0..31
  const int s = tid & 7;
  float tp = 0.f;
  float x = 0.f;
#pragma unroll
  for (int j0 = 0; j0 < 3; ++j0) {
    const int j = s + j0 * 8;
    if (j < F4_ROW) {
      const f4 o = lds_o[r * F4_ROW + j];
      const f4 g = lds_g[r * F4_ROW + j];
      {
        const float pf = (o.x > 0.f) ? 1.f : 0.f;
        x += fabsf(pf - g.x);
        tp = fmaf(pf, g.x, tp);
      }
      {
        const float pf = (o.y > 0.f) ? 1.f : 0.f;
        x += fabsf(pf - g.y);
        tp = fmaf(pf, g.y, tp);
      }
      {
        const float pf = (o.z > 0.f) ? 1.f : 0.f;
        x += fabsf(pf - g.z);
        tp = fmaf(pf, g.z, tp);
      }
      {
        const float pf = (o.w > 0.f) ? 1.f : 0.f;
        x += fabsf(pf - g.w);
        tp = fmaf(pf, g.w, tp);
      }
    }
  }
  // fpfn: reduce across the 8 lanes of this row (contiguous lanes)
  x += __shfl_down(x, 4, 64);
  x += __shfl_down(x, 2, 64);
  x += __shfl_down(x, 1, 64);
  if (s == 0) fpfn[(size_t)blk * ROWS + r] = x;

  // tp: wave reduce + cross-wave, deterministic per-block partial
  for (int off = 32; off > 0; off >>= 1) tp += __shfl_down(tp, off, 64);
  if (lane == 0) s_tp[wave] = tp;
  __syncthreads();
  if (tid == 0) tp_part[blk] = s_tp[0] + s_tp[1] + s_tp[2] + s_tp[3];
}

// K2: one block per n; computes acc[n] and atomicAdds into out[0]
// (blocks finish staggered -> negligible same-address contention).
__global__ __launch_bounds__(256) void acc_finalize_kernel(
    const int* __restrict__ mask, const float* __restrict__ fpfn,
    const float* __restrict__ tp_part, float* __restrict__ out) {
  const int n = blockIdx.x;
  const int tid = threadIdx.x;
  __shared__ float sa[256], sb[256];

  // T_i via int4 loads (2048 ints = 512 int4)
  const int4* m4 = (const int4*)(mask + (size_t)n * TT);
  int ti = 0;
#pragma unroll
  for (int it = 0; it < 2; ++it) {
    const int4 v = m4[it * 256 + tid];
    ti += v.x + v.y + v.z + v.w;
  }
  const float tpv = (tid < PARTS_PER_N) ? tp_part[n * PARTS_PER_N + tid] : 0.f;

  sa[tid] = (float)ti;
  sb[tid] = tpv;
  __syncthreads();
  for (int s = 128; s > 0; s >>= 1) {
    if (tid < s) { sa[tid] += sa[tid + s]; sb[tid] += sb[tid + s]; }
    __syncthreads();
  }
  const float fTi = sa[0];
  const float tp = sb[0];
  const int Ti = (int)fTi;
  __syncthreads();

  const float* __restrict__ fr = fpfn + (size_t)n * TT;
  float a = 0.f;
  for (int t = tid; t < Ti; t += 256) a += tp / (tp + fr[t]);
  sa[tid] = a;
  __syncthreads();
  for (int s = 128; s > 0; s >>= 1) {
    if (tid < s) sa[tid] += sa[tid + s];
    __syncthreads();
  }
  if (tid == 0) atomicAdd(out, sa[0] / fTi);
}

extern "C" void kernel_launch(void* const* d_in, const int* in_sizes, int n_in,
                              void* d_out, int out_size, void* d_ws, size_t ws_size,
                              hipStream_t stream) {
  const float* output = (const float*)d_in[0];
  const float* target = (const float*)d_in[1];
  const int* mask = (const int*)d_in[2];
  float* out = (float*)d_out;

  float* tp_part = (float*)d_ws;          // K1_BLOCKS floats
  float* fpfn = tp_part + K1_BLOCKS;      // N*T floats

  hipMemsetAsync(d_out, 0, sizeof(float) * out_size, stream);
  acc_rowstats_kernel<<<K1_BLOCKS, 256, 0, stream>>>(output, target, fpfn, tp_part);
  acc_finalize_kernel<<<NN, 256, 0, stream>>>(mask, fpfn, tp_part, out);
}